// Round 3
// baseline (6331.680 us; speedup 1.0000x reference)
//
#include <hip/hip_runtime.h>

#define BB   128   // batch
#define TT   1024  // time steps
#define INP  256   // input dim
#define HH   512   // hidden dim
#define OUTD 256   // output dim
#define GB   16    // batches per group (group = XCD)
#define NG   8     // groups = XCDs
#define NBLK 256   // 32 candidates/XCD, 8 claim roles, rest exit

typedef float  f32x4  __attribute__((ext_vector_type(4)));
typedef short  short8 __attribute__((ext_vector_type(8)));
typedef unsigned long long u64;

__device__ __forceinline__ unsigned short bf16_rne(float f) {
  union { float f; unsigned u; } v; v.f = f;
  unsigned r = v.u + 0x7fffu + ((v.u >> 16) & 1u);
  return (unsigned short)(r >> 16);
}

// tanh(x) = 1 - 2/(e^{2x}+1) via v_exp_f32 + v_rcp_f32. Abs err ~1e-7,
// far below the bf16 h-state quantization already in the pipeline.
__device__ __forceinline__ float fast_tanh(float x) {
  float t = __builtin_amdgcn_exp2f(x * 2.8853900817779268f); // 2*log2(e)
  return 1.0f - 2.0f * __builtin_amdgcn_rcpf(t + 1.0f);
}

__device__ __forceinline__ short8 pack8(f32x4 a, f32x4 b) {
  union { unsigned short s[8]; short8 v; } u;
  u.s[0] = bf16_rne(a[0]); u.s[1] = bf16_rne(a[1]);
  u.s[2] = bf16_rne(a[2]); u.s[3] = bf16_rne(a[3]);
  u.s[4] = bf16_rne(b[0]); u.s[5] = bf16_rne(b[1]);
  u.s[6] = bf16_rne(b[2]); u.s[7] = bf16_rne(b[3]);
  return u.v;
}

__device__ __forceinline__ short8 load_cvt8(const float* p) {
  const f32x4* q = (const f32x4*)p;
  return pack8(q[0], q[1]);
}

__device__ __forceinline__ f32x4 ntload4(const float* p) {
  return __builtin_nontemporal_load((const f32x4*)p);
}

// XCD-local L2 h-state load: agent-scope RELAXED atomic -> sc0 (L1 bypass),
// compiler batches many outstanding loads under one waitcnt.
__device__ __forceinline__ short8 l2load8(const unsigned short* p) {
  union { u64 q[2]; short8 v; } u;
  const u64* pp = (const u64*)p;
  u.q[0] = __hip_atomic_load(pp,     __ATOMIC_RELAXED, __HIP_MEMORY_SCOPE_AGENT);
  u.q[1] = __hip_atomic_load(pp + 1, __ATOMIC_RELAXED, __HIP_MEMORY_SCOPE_AGENT);
  return u.v;
}

// h-state fragment slots: per (slot, group): [kb(16)][lane(64)][e(8)] bf16 = 16KB.
// Value (b_local, j): kb = j>>5, lane' = ((j>>3)&3)*16 + b_local, e = j&7.
// 4-slot rings. Merged-block flag scheme slot-safety: a block entering tick t
// has seen all flag0 >= t+1, i.e. every peer finished ALL of tick t-2 (incl.
// its L1 section), so all readers of h0(t-4)/h1(t-5) (tick t-3) are done
// before this tick's writes to slot t&3 / (t+3)&3.
__device__ __forceinline__ unsigned short* hslot(unsigned short* base, int slot, int g) {
  return base + ((size_t)(slot * NG + g)) * (16 * 64 * 8);
}

__global__ void __launch_bounds__(256, 1) rnn_mfma(
    const float* __restrict__ x,       // [B][T][IN]
    const float* __restrict__ h0init,  // [2][B][H]
    const float* __restrict__ w_ih0,   // [H][IN]
    const float* __restrict__ w_hh0,   // [H][H]
    const float* __restrict__ b_ih0,   // [H]
    const float* __restrict__ b_hh0,   // [H]
    const float* __restrict__ w_ih1,   // [H][H]
    const float* __restrict__ w_hh1,   // [H][H]
    const float* __restrict__ b_ih1,   // [H]
    const float* __restrict__ b_hh1,   // [H]
    const float* __restrict__ fc_w,    // [OUT][H]
    const float* __restrict__ fc_b,    // [OUT]
    float* __restrict__ out,           // [B][OUT]
    unsigned* __restrict__ ws_ctl,     // tickets: [g*32]; flags: +1024 u32, per group 16 x 128B
    unsigned short* __restrict__ h0f,  // h0 ring: 4 slots x NG x 16KB
    unsigned short* __restrict__ h1f)  // h1 ring: 4 slots x NG x 16KB
{
  const int tid = threadIdx.x;

  // ---- claim a role on THIS XCD.
  __shared__ unsigned sh_tk, sh_g;
  if (tid == 0) {
    unsigned xcc;
    asm volatile("s_getreg_b32 %0, hwreg(HW_REG_XCC_ID)" : "=s"(xcc));
    xcc &= 7;
    sh_g  = xcc;
    sh_tk = __hip_atomic_fetch_add(ws_ctl + xcc * 32, 1u,
                                   __ATOMIC_RELAXED, __HIP_MEMORY_SCOPE_AGENT);
  }
  __syncthreads();
  const unsigned ticket = sh_tk;
  const int g = (int)sh_g;
  if (ticket >= 8) return;             // 8 merged roles per XCD; spares exit

  const int role = (int)ticket;        // j-slice [role*64, role*64+64) of BOTH layers
  const int wv   = tid >> 6;
  const int lane = tid & 63;
  const int ln   = lane & 15;
  const int q    = lane >> 4;
  const int j0   = role * 64 + wv * 16 + ln;   // weight-frag row (m = lane&15)
  const int jq   = role * 64 + wv * 16 + q * 4; // this thread's 4 output j's
  const int bg   = g * GB;

  // Per-block flag lines. flag0 (lines 0..7): h0 progress; = t+2 after h0(t)
  // stored+drained. flag1 (lines 8..15): h1 progress; = t+2 after tick t's L1
  // section (h1(t-1)) stored+drained.
  volatile int* flags  = (volatile int*)(ws_ctl + 1024 + g * 512);
  volatile int* flag0p = flags + role * 32;
  volatile int* flag1p = flags + (8 + role) * 32;

  // ---- init: h0init -> h0 slot 3, h1init -> h1 slot 3 (redundant across blocks, benign).
  for (int c = tid; c < 2048; c += 256) {
    int a  = c >> 10;
    int bl = (c >> 6) & 15;
    int j8 = (c & 63) * 8;
    short8 v = load_cvt8(h0init + ((size_t)a * BB + (bg + bl)) * HH + j8);
    unsigned short* dst = hslot(a ? h1f : h0f, 3, g)
        + ((size_t)((j8 >> 5) * 64 + ((j8 >> 3) & 3) * 16 + bl)) * 8;
    *(short8*)dst = v;
  }
  __syncthreads();                     // drain init stores to L2
  if (tid == 0) { *flag0p = 1; *flag1p = 1; }

  // ---- BOTH layers' weight A-fragments -> registers (row j0, k = kb*32+q*8+e).
  short8 Bf0[24];  // L0: w_ih0 (kb 0..7) then w_hh0 (kb 8..23)  : 96 VGPR
  short8 Bf1[32];  // L1: w_ih1 (kb 0..15) then w_hh1 (kb 16..31): 128 VGPR
#pragma unroll
  for (int kb = 0; kb < 24; ++kb) {
    int k = kb * 32 + q * 8;
    const float* src = (k < INP) ? (w_ih0 + (size_t)j0 * INP + k)
                                 : (w_hh0 + (size_t)j0 * HH + (k - INP));
    Bf0[kb] = load_cvt8(src);
  }
#pragma unroll
  for (int kb = 0; kb < 32; ++kb) {
    int k = kb * 32 + q * 8;
    const float* src = (k < HH) ? (w_ih1 + (size_t)j0 * HH + k)
                                : (w_hh1 + (size_t)j0 * HH + (k - HH));
    Bf1[kb] = load_cvt8(src);
  }
  const f32x4 bias0 = *(const f32x4*)(b_ih0 + jq) + *(const f32x4*)(b_hh0 + jq);
  const f32x4 bias1 = *(const f32x4*)(b_ih1 + jq) + *(const f32x4*)(b_hh1 + jq);

  short8 xa[8];
  {
    const float* xp = x + ((size_t)(bg + ln) * TT + 0) * INP;
#pragma unroll
    for (int kb = 0; kb < 8; ++kb)
      xa[kb] = pack8(ntload4(xp + kb * 32 + q * 8), ntload4(xp + kb * 32 + q * 8 + 4));
  }

  const f32x4 z = {0.f, 0.f, 0.f, 0.f};

  // ---- tick loop. Tick t: C0: h0(t) = f(x(t), h0(t-1)); publish flag0.
  //                         C1: h1(t-1) = f(h0(t-1), h1(t-2)); publish flag1.
  // C1 (incl. its loads and the x(t+1) prefetch) runs inside the window where
  // peers are polling/loading -> off the critical cycle.
#pragma unroll 1
  for (int t = 0; t <= TT; ++t) {
    // C0 gate: h0(t-1) ready from all peers.
    if (tid < 8) {
      volatile int* fp = flags + tid * 32;
      const int thr = t + 1;
      while (*fp < thr) __builtin_amdgcn_s_sleep(1);
    }
    __syncthreads();

    // h0(t-1) fragments: used by L0's w_hh0 part AND L1's w_ih1 part.
    const unsigned short* hp0 = hslot(h0f, (t + 3) & 3, g);
    short8 Af0[16];
#pragma unroll
    for (int kb = 0; kb < 16; ++kb)
      Af0[kb] = l2load8(hp0 + ((size_t)kb * 64 + lane) * 8);

    if (t < TT) {
      f32x4 ac[4] = {z, z, z, z};
#pragma unroll
      for (int kb = 0; kb < 8; ++kb)   // x part first: runs while Af0 in flight
        ac[kb & 3] = __builtin_amdgcn_mfma_f32_16x16x32_bf16(
            Bf0[kb], xa[kb], ac[kb & 3], 0, 0, 0);
#pragma unroll
      for (int kb = 8; kb < 24; ++kb)
        ac[kb & 3] = __builtin_amdgcn_mfma_f32_16x16x32_bf16(
            Bf0[kb], Af0[kb - 8], ac[kb & 3], 0, 0, 0);
      f32x4 d = ac[0] + ac[1] + ac[2] + ac[3];
      unsigned short* wdst = hslot(h0f, t & 3, g);
      union { unsigned short s[4]; u64 q8; } uu;
#pragma unroll
      for (int r = 0; r < 4; ++r)
        uu.s[r] = bf16_rne(fast_tanh(d[r] + bias0[r]));
      *(u64*)(wdst + (size_t)((jq >> 5) * 64 + ((jq >> 3) & 3) * 16 + ln) * 8
              + (jq & 7)) = uu.q8;
    }

    // flag1 gate for h1(t-2): one tick stale in steady state -> ~never spins.
    // Poll overlaps the h0 store drain; the barrier then drains stores so
    // flag0 can be published immediately after.
    if (tid < 8) {
      volatile int* fp = flags + (8 + tid) * 32;
      const int thr = t + 1;
      while (*fp < thr) __builtin_amdgcn_s_sleep(1);
    }
    __syncthreads();                   // drains h0(t) stores to L2
    if (tid == 0 && t < TT) *flag0p = t + 2;

    // ---- C1 (hidden window): x(t+1) prefetch issued first, then h1 work.
    f32x4 xr[16];
    const bool havex = (t + 1 < TT);
    if (havex) {
      const float* xp = x + ((size_t)(bg + ln) * TT + (t + 1)) * INP;
#pragma unroll
      for (int kb = 0; kb < 8; ++kb) {
        xr[2 * kb]     = ntload4(xp + kb * 32 + q * 8);
        xr[2 * kb + 1] = ntload4(xp + kb * 32 + q * 8 + 4);
      }
    }
    if (t >= 1) {
      const unsigned short* hp1 = hslot(h1f, (t + 2) & 3, g);  // h1(t-2)
      short8 Af1[16];
#pragma unroll
      for (int kb = 0; kb < 16; ++kb)
        Af1[kb] = l2load8(hp1 + ((size_t)kb * 64 + lane) * 8);

      f32x4 ac[4] = {z, z, z, z};
#pragma unroll
      for (int kb = 0; kb < 16; ++kb)  // reuses Af0 (h0(t-1)) already in regs
        ac[kb & 3] = __builtin_amdgcn_mfma_f32_16x16x32_bf16(
            Bf1[kb], Af0[kb], ac[kb & 3], 0, 0, 0);
#pragma unroll
      for (int kb = 0; kb < 16; ++kb)
        ac[kb & 3] = __builtin_amdgcn_mfma_f32_16x16x32_bf16(
            Bf1[kb + 16], Af1[kb], ac[kb & 3], 0, 0, 0);
      f32x4 d = ac[0] + ac[1] + ac[2] + ac[3];
      unsigned short* wdst = hslot(h1f, (t + 3) & 3, g);  // h1(t-1)
      union { unsigned short s[4]; u64 q8; } uu;
#pragma unroll
      for (int r = 0; r < 4; ++r)
        uu.s[r] = bf16_rne(fast_tanh(d[r] + bias1[r]));
      *(u64*)(wdst + (size_t)((jq >> 5) * 64 + ((jq >> 3) & 3) * 16 + ln) * 8
              + (jq & 7)) = uu.q8;
    }
    if (havex) {
#pragma unroll
      for (int kb = 0; kb < 8; ++kb)
        xa[kb] = pack8(xr[2 * kb], xr[2 * kb + 1]);
    }
    __syncthreads();                   // drains h1 stores
    if (tid == 0) *flag1p = t + 2;
  }

  // ---- FC epilogue: out = h1(TT-1) @ fc_w^T + fc_b (slot 3).
  if (tid < 8) {
    volatile int* fp = flags + (8 + tid) * 32;
    while (*fp < TT + 2) __builtin_amdgcn_s_sleep(1);
  }
  __syncthreads();

  if (wv < 2) {
    const unsigned short* hp = hslot(h1f, 3, g);
    const int ot   = role * 2 + wv;       // 16 o-tiles across 8 blocks x 2 waves
    const int o_ln = ot * 16 + ln;        // fc_w frag row (A-operand, m = ln)
    const int o_q  = ot * 16 + q * 4;     // this thread's 4 output cols
    f32x4 ac[4] = {z, z, z, z};
#pragma unroll
    for (int kb = 0; kb < 16; ++kb) {
      int k = kb * 32 + q * 8;
      short8 Bfc = load_cvt8(fc_w + (size_t)o_ln * HH + k);
      short8 Af  = l2load8(hp + ((size_t)kb * 64 + lane) * 8);
      ac[kb & 3] = __builtin_amdgcn_mfma_f32_16x16x32_bf16(
          Bfc, Af, ac[kb & 3], 0, 0, 0);
    }
    f32x4 fb = *(const f32x4*)(fc_b + o_q);
    f32x4 v = ac[0] + ac[1] + ac[2] + ac[3] + fb;
    *(f32x4*)(out + (size_t)(bg + ln) * OUTD + o_q) = v;
  }
}

extern "C" void kernel_launch(void* const* d_in, const int* in_sizes, int n_in,
                              void* d_out, int out_size, void* d_ws, size_t ws_size,
                              hipStream_t stream) {
  (void)in_sizes; (void)n_in; (void)out_size; (void)ws_size;

  const float* x      = (const float*)d_in[0];
  const float* h0init = (const float*)d_in[1];
  const float* w_ih0  = (const float*)d_in[2];
  const float* w_hh0  = (const float*)d_in[3];
  const float* b_ih0  = (const float*)d_in[4];
  const float* b_hh0  = (const float*)d_in[5];
  const float* w_ih1  = (const float*)d_in[6];
  const float* w_hh1  = (const float*)d_in[7];
  const float* b_ih1  = (const float*)d_in[8];
  const float* b_hh1  = (const float*)d_in[9];
  const float* fc_w   = (const float*)d_in[10];
  const float* fc_b   = (const float*)d_in[11];
  float* out = (float*)d_out;

  // ws: [0,32768) tickets + flags (zeroed); then h0 ring 512KB; h1 ring 512KB
  unsigned* ws_ctl = (unsigned*)d_ws;
  unsigned short* h0f = (unsigned short*)((char*)d_ws + 32768);
  unsigned short* h1f = h0f + 4 * NG * (16 * 64 * 8);

  hipMemsetAsync(d_ws, 0, 32768, stream);

  rnn_mfma<<<dim3(NBLK), dim3(256), 0, stream>>>(
      x, h0init, w_ih0, w_hh0, b_ih0, b_hh0, w_ih1, w_hh1, b_ih1, b_hh1,
      fc_w, fc_b, out, ws_ctl, h0f, h1f);
}

// Round 4
// 4613.320 us; speedup vs baseline: 1.3725x; 1.3725x over previous
//
#include <hip/hip_runtime.h>

#define BB   128   // batch
#define TT   1024  // time steps
#define INP  256   // input dim
#define HH   512   // hidden dim
#define OUTD 256   // output dim
#define GB   16    // batches per group (group = XCD)
#define NG   8     // groups = XCDs
#define NBLK 256   // 1 per CU (88KB LDS cap) -> bijection -> 32 blocks/XCD

typedef float  f32x4  __attribute__((ext_vector_type(4)));
typedef short  short8 __attribute__((ext_vector_type(8)));
typedef unsigned long long u64;

__device__ __forceinline__ unsigned short bf16_rne(float f) {
  union { float f; unsigned u; } v; v.f = f;
  unsigned r = v.u + 0x7fffu + ((v.u >> 16) & 1u);
  return (unsigned short)(r >> 16);
}

// tanh(x) = 1 - 2/(e^{2x}+1) via v_exp_f32 + v_rcp_f32. Abs err ~1e-7,
// far below the bf16 h-state quantization already in the pipeline.
__device__ __forceinline__ float fast_tanh(float x) {
  float t = __builtin_amdgcn_exp2f(x * 2.8853900817779268f); // 2*log2(e)
  return 1.0f - 2.0f * __builtin_amdgcn_rcpf(t + 1.0f);
}

__device__ __forceinline__ short8 pack8(f32x4 a, f32x4 b) {
  union { unsigned short s[8]; short8 v; } u;
  u.s[0] = bf16_rne(a[0]); u.s[1] = bf16_rne(a[1]);
  u.s[2] = bf16_rne(a[2]); u.s[3] = bf16_rne(a[3]);
  u.s[4] = bf16_rne(b[0]); u.s[5] = bf16_rne(b[1]);
  u.s[6] = bf16_rne(b[2]); u.s[7] = bf16_rne(b[3]);
  return u.v;
}

__device__ __forceinline__ short8 load_cvt8(const float* p) {
  const f32x4* q = (const f32x4*)p;
  return pack8(q[0], q[1]);
}

__device__ __forceinline__ f32x4 ntload4(const float* p) {
  return __builtin_nontemporal_load((const f32x4*)p);
}

// XCD-local L2 h-state load: agent-scope RELAXED atomic -> sc0 (L1 bypass),
// compiler batches many outstanding loads under one waitcnt.
__device__ __forceinline__ short8 l2load8(const unsigned short* p) {
  union { u64 q[2]; short8 v; } u;
  const u64* pp = (const u64*)p;
  u.q[0] = __hip_atomic_load(pp,     __ATOMIC_RELAXED, __HIP_MEMORY_SCOPE_AGENT);
  u.q[1] = __hip_atomic_load(pp + 1, __ATOMIC_RELAXED, __HIP_MEMORY_SCOPE_AGENT);
  return u.v;
}

// h-state fragment slots: per (slot, group): [kb(16)][lane(64)][e(8)] bf16 = 16KB.
// Value (b_local, j): kb = j>>5, lane' = ((j>>3)&3)*16 + b_local, e = j&7.
// 4-slot rings. Writer/reader distance bounds under flag scheme: L0-peer lead
// <=1 tick, L0-over-L1 lead <=3 ticks -> no slot collision (checked mod 4).
__device__ __forceinline__ unsigned short* hslot(unsigned short* base, int slot, int g) {
  return base + ((size_t)(slot * NG + g)) * (16 * 64 * 8);
}

__global__ void __launch_bounds__(256, 1) rnn_mfma(
    const float* __restrict__ x,       // [B][T][IN]
    const float* __restrict__ h0init,  // [2][B][H]
    const float* __restrict__ w_ih0,   // [H][IN]
    const float* __restrict__ w_hh0,   // [H][H]
    const float* __restrict__ b_ih0,   // [H]
    const float* __restrict__ b_hh0,   // [H]
    const float* __restrict__ w_ih1,   // [H][H]
    const float* __restrict__ w_hh1,   // [H][H]
    const float* __restrict__ b_ih1,   // [H]
    const float* __restrict__ b_hh1,   // [H]
    const float* __restrict__ fc_w,    // [OUT][H]
    const float* __restrict__ fc_b,    // [OUT]
    float* __restrict__ out,           // [B][OUT]
    unsigned* __restrict__ ws_ctl,     // tickets: [g*32]; done: [16]; flags: +1024 u32
    unsigned short* __restrict__ h0f,  // h0 ring: 4 slots x NG x 16KB
    unsigned short* __restrict__ h1f)  // h1 ring: 4 slots x NG x 16KB
{
  extern __shared__ char lds_pad[];    // 88KB dynamic -> occupancy cap (1 block/CU)
  (void)lds_pad;
  const int tid = threadIdx.x;

  // ---- claim a role on THIS XCD.
  __shared__ unsigned sh_tk, sh_g;
  if (tid == 0) {
    unsigned xcc;
    asm volatile("s_getreg_b32 %0, hwreg(HW_REG_XCC_ID)" : "=s"(xcc));
    xcc &= 7;
    sh_g  = xcc;
    sh_tk = __hip_atomic_fetch_add(ws_ctl + xcc * 32, 1u,
                                   __ATOMIC_RELAXED, __HIP_MEMORY_SCOPE_AGENT);
  }
  __syncthreads();
  const unsigned ticket = sh_tk;
  const int g = (int)sh_g;

  if (ticket >= 16) {
    // ---- spare block: DPM clock-holder. Spin independent-chain FMAs (high
    // issue activity, zero memory traffic) on this otherwise-idle CU until
    // all 8 groups have finished their FC epilogue (done counter == NG).
    // Workers never depend on spares; exit is guaranteed.
    const unsigned* donep = ws_ctl + 16;
    float a0 = (float)tid * 1.25f + 0.5f, a1 = a0 + 1.0f, a2 = a0 + 2.0f,
          a3 = a0 + 3.0f, a4 = a0 + 4.0f, a5 = a0 + 5.0f, a6 = a0 + 6.0f,
          a7 = a0 + 7.0f;
    const float m = 0.99993896484375f, c = 1.52587890625e-05f;
    while (__hip_atomic_load(donep, __ATOMIC_RELAXED,
                             __HIP_MEMORY_SCOPE_AGENT) < NG) {
#pragma unroll
      for (int it = 0; it < 64; ++it) {
        a0 = __builtin_fmaf(a0, m, c); a1 = __builtin_fmaf(a1, m, c);
        a2 = __builtin_fmaf(a2, m, c); a3 = __builtin_fmaf(a3, m, c);
        a4 = __builtin_fmaf(a4, m, c); a5 = __builtin_fmaf(a5, m, c);
        a6 = __builtin_fmaf(a6, m, c); a7 = __builtin_fmaf(a7, m, c);
      }
    }
    // keep the chains live; ws scratch word, never interpreted.
    if (tid == 0)
      ((volatile float*)(ws_ctl + 240))[0] = a0 + a1 + a2 + a3 + a4 + a5 + a6 + a7;
    return;
  }

  const int role = (int)ticket;        // 0..7: L0 j-slices; 8..15: L1 j-slices
  const bool isL0 = role < 8;
  const int wv   = tid >> 6;
  const int lane = tid & 63;
  const int ln   = lane & 15;
  const int q    = lane >> 4;
  const int j0   = (role & 7) * 64 + wv * 16 + ln;  // weight-frag row (m = lane&15)
  const int jq   = (role & 7) * 64 + wv * 16 + q * 4; // this thread's 4 output j's
  const int bg   = g * GB;

  // Per-block flag lines: flag[b] = 1 after init; = t+2 after completing tick t.
  volatile int* flags  = (volatile int*)(ws_ctl + 1024 + g * 512);
  volatile int* myflag = flags + role * 32;

  // ---- init: h0init -> h0 slot 3, h1init -> h1 slot 3 (plain stores, local L2).
  for (int c = tid; c < 2048; c += 256) {
    int a  = c >> 10;
    int bl = (c >> 6) & 15;
    int j8 = (c & 63) * 8;
    short8 v = load_cvt8(h0init + ((size_t)a * BB + (bg + bl)) * HH + j8);
    unsigned short* dst = hslot(a ? h1f : h0f, 3, g)
        + ((size_t)((j8 >> 5) * 64 + ((j8 >> 3) & 3) * 16 + bl)) * 8;
    *(short8*)dst = v;
  }
  __syncthreads();                     // drain init stores to L2
  if (tid == 0) *myflag = 1;           // init published

  // ---- weight fragments -> registers (MFMA A-operand; row j0, k = kb*32+q*8+e).
  short8 Bf0[24];  // L0: w_ih0 (kb 0..7) then w_hh0 (kb 8..23)
  short8 Bf1[32];  // L1: w_ih1 (kb 0..15) then w_hh1 (kb 16..31)
  if (isL0) {
#pragma unroll
    for (int kb = 0; kb < 24; ++kb) {
      int k = kb * 32 + q * 8;
      const float* src = (k < INP) ? (w_ih0 + (size_t)j0 * INP + k)
                                   : (w_hh0 + (size_t)j0 * HH + (k - INP));
      Bf0[kb] = load_cvt8(src);
    }
  } else {
#pragma unroll
    for (int kb = 0; kb < 32; ++kb) {
      int k = kb * 32 + q * 8;
      const float* src = (k < HH) ? (w_ih1 + (size_t)j0 * HH + k)
                                  : (w_hh1 + (size_t)j0 * HH + (k - HH));
      Bf1[kb] = load_cvt8(src);
    }
  }
  // Per-thread bias vector for its 4 output j's (jq+0..3). 16B-aligned loads.
  f32x4 bias4;
  {
    const float* bi = isL0 ? b_ih0 : b_ih1;
    const float* bh = isL0 ? b_hh0 : b_hh1;
    bias4 = *(const f32x4*)(bi + jq) + *(const f32x4*)(bh + jq);
  }

  short8 xa[8];
  if (isL0) {
    const float* xp = x + ((size_t)(bg + ln) * TT + 0) * INP;
#pragma unroll
    for (int kb = 0; kb < 8; ++kb)
      xa[kb] = pack8(ntload4(xp + kb * 32 + q * 8), ntload4(xp + kb * 32 + q * 8 + 4));
  }

  const f32x4 z = {0.f, 0.f, 0.f, 0.f};
  const int tmax = isL0 ? (TT - 1) : TT;

  // ---- tick loop. L0 tick t: h0(t) = f(x(t), h0(t-1)). Waits: L0 flags >= t+1,
  // L1 flags >= t-1 (slot-reuse guard). L1 tick t (>=1): h1(t-1) =
  // f(h0(t-1), h1(t-2)). Waits: L0,L1 flags >= t+1.
#pragma unroll 1
  for (int t = 0; t <= tmax; ++t) {
    {
      const int thrL0 = t + 1;
      const int thrL1 = isL0 ? (t - 1) : (t + 1);
      if (tid < 16) {
        volatile int* fp = flags + tid * 32;
        const int thr = (tid < 8) ? thrL0 : thrL1;
        while (*fp < thr) __builtin_amdgcn_s_sleep(1);
      }
      __syncthreads();
    }

    if (isL0) {
      const unsigned short* hp0 = hslot(h0f, (t + 3) & 3, g);  // h0(t-1)
      short8 Af[16];
#pragma unroll
      for (int kb = 0; kb < 16; ++kb)
        Af[kb] = l2load8(hp0 + ((size_t)kb * 64 + lane) * 8);

      // x(t+1) NT loads issued early: complete during MFMAs
      f32x4 xr[16];
      if (t + 1 < TT) {
        const float* xp = x + ((size_t)(bg + ln) * TT + (t + 1)) * INP;
#pragma unroll
        for (int kb = 0; kb < 8; ++kb) {
          xr[2 * kb]     = ntload4(xp + kb * 32 + q * 8);
          xr[2 * kb + 1] = ntload4(xp + kb * 32 + q * 8 + 4);
        }
      }

      f32x4 ac[4] = {z, z, z, z};
#pragma unroll
      for (int kb = 0; kb < 8; ++kb)
        ac[kb & 3] = __builtin_amdgcn_mfma_f32_16x16x32_bf16(
            Bf0[kb], xa[kb], ac[kb & 3], 0, 0, 0);
#pragma unroll
      for (int kb = 8; kb < 24; ++kb)
        ac[kb & 3] = __builtin_amdgcn_mfma_f32_16x16x32_bf16(
            Bf0[kb], Af[kb - 8], ac[kb & 3], 0, 0, 0);

      f32x4 d = ac[0] + ac[1] + ac[2] + ac[3];
      // D[m = q*4+r][n = ln]: 4 consecutive j (jq..jq+3), batch = ln.
      // One aligned 8B store; wave's 64x8B fully covers two 256B segments.
      unsigned short* wdst = hslot(h0f, t & 3, g);
      union { unsigned short s[4]; u64 q8; } uu;
#pragma unroll
      for (int r = 0; r < 4; ++r)
        uu.s[r] = bf16_rne(fast_tanh(d[r] + bias4[r]));
      *(u64*)(wdst + (size_t)((jq >> 5) * 64 + ((jq >> 3) & 3) * 16 + ln) * 8
              + (jq & 7)) = uu.q8;
      if (t + 1 < TT) {
#pragma unroll
        for (int kb = 0; kb < 8; ++kb)
          xa[kb] = pack8(xr[2 * kb], xr[2 * kb + 1]);
      }
    } else if (t >= 1) {
      const unsigned short* hp0 = hslot(h0f, (t + 3) & 3, g);  // h0(t-1)
      const unsigned short* hp1 = hslot(h1f, (t + 2) & 3, g);  // h1(t-2)
      // batch ALL 32 A-frag loads before any MFMA (one waitcnt, pipelined)
      short8 Af0[16], Af1[16];
#pragma unroll
      for (int kb = 0; kb < 16; ++kb)
        Af0[kb] = l2load8(hp0 + ((size_t)kb * 64 + lane) * 8);
#pragma unroll
      for (int kb = 0; kb < 16; ++kb)
        Af1[kb] = l2load8(hp1 + ((size_t)kb * 64 + lane) * 8);

      f32x4 ac[4] = {z, z, z, z};
#pragma unroll
      for (int kb = 0; kb < 16; ++kb)
        ac[kb & 3] = __builtin_amdgcn_mfma_f32_16x16x32_bf16(
            Bf1[kb], Af0[kb], ac[kb & 3], 0, 0, 0);
#pragma unroll
      for (int kb = 0; kb < 16; ++kb)
        ac[kb & 3] = __builtin_amdgcn_mfma_f32_16x16x32_bf16(
            Bf1[kb + 16], Af1[kb], ac[kb & 3], 0, 0, 0);

      f32x4 d = ac[0] + ac[1] + ac[2] + ac[3];
      unsigned short* wdst = hslot(h1f, (t + 3) & 3, g);  // h1(t-1)
      union { unsigned short s[4]; u64 q8; } uu;
#pragma unroll
      for (int r = 0; r < 4; ++r)
        uu.s[r] = bf16_rne(fast_tanh(d[r] + bias4[r]));
      *(u64*)(wdst + (size_t)((jq >> 5) * 64 + ((jq >> 3) & 3) * 16 + ln) * 8
              + (jq & 7)) = uu.q8;
    }

    __syncthreads();                   // drain this tick's h stores to L2
    if (tid == 0) *myflag = t + 2;     // publish tick completion
  }

  // ---- FC epilogue: out = h1(TT-1) @ fc_w^T + fc_b (slot 3). Wait for all
  // L1 blocks to finish tick TT (flag = TT+2); L0 flags end at TT+1.
  if (tid < 16) {
    volatile int* fp = flags + tid * 32;
    const int thr = (tid < 8) ? (TT + 1) : (TT + 2);
    while (*fp < thr) __builtin_amdgcn_s_sleep(1);
  }
  __syncthreads();

  if (wv == 0) {
    const unsigned short* hp = hslot(h1f, 3, g);
    const int o_ln = role * 16 + ln;      // fc_w frag row (A-operand, m = ln)
    const int o_q  = role * 16 + q * 4;   // this thread's 4 output cols
    f32x4 ac[4] = {z, z, z, z};
#pragma unroll
    for (int kb = 0; kb < 16; ++kb) {
      int k = kb * 32 + q * 8;
      short8 Bfc = load_cvt8(fc_w + (size_t)o_ln * HH + k);
      short8 Af  = l2load8(hp + ((size_t)kb * 64 + lane) * 8);
      ac[kb & 3] = __builtin_amdgcn_mfma_f32_16x16x32_bf16(
          Bfc, Af, ac[kb & 3], 0, 0, 0);
    }
    // D[m = q*4+r][n = ln]: out[bg+ln][o_q + r] -> one 16B coalesced store.
    f32x4 fb = *(const f32x4*)(fc_b + o_q);
    f32x4 v = ac[0] + ac[1] + ac[2] + ac[3] + fb;
    *(f32x4*)(out + (size_t)(bg + ln) * OUTD + o_q) = v;
  }

  // signal spares: this group done (one add per group, after FC).
  __syncthreads();
  if (role == 0 && tid == 0)
    __hip_atomic_fetch_add(ws_ctl + 16, 1u,
                           __ATOMIC_RELAXED, __HIP_MEMORY_SCOPE_AGENT);
}

extern "C" void kernel_launch(void* const* d_in, const int* in_sizes, int n_in,
                              void* d_out, int out_size, void* d_ws, size_t ws_size,
                              hipStream_t stream) {
  (void)in_sizes; (void)n_in; (void)out_size; (void)ws_size;

  const float* x      = (const float*)d_in[0];
  const float* h0init = (const float*)d_in[1];
  const float* w_ih0  = (const float*)d_in[2];
  const float* w_hh0  = (const float*)d_in[3];
  const float* b_ih0  = (const float*)d_in[4];
  const float* b_hh0  = (const float*)d_in[5];
  const float* w_ih1  = (const float*)d_in[6];
  const float* w_hh1  = (const float*)d_in[7];
  const float* b_ih1  = (const float*)d_in[8];
  const float* b_hh1  = (const float*)d_in[9];
  const float* fc_w   = (const float*)d_in[10];
  const float* fc_b   = (const float*)d_in[11];
  float* out = (float*)d_out;

  // ws: [0,32768) tickets + done + flags (zeroed); then h0 ring 512KB; h1 ring 512KB
  unsigned* ws_ctl = (unsigned*)d_ws;
  unsigned short* h0f = (unsigned short*)((char*)d_ws + 32768);
  unsigned short* h1f = h0f + 4 * NG * (16 * 64 * 8);

  hipMemsetAsync(d_ws, 0, 32768, stream);

  rnn_mfma<<<dim3(NBLK), dim3(256), 90112, stream>>>(
      x, h0init, w_ih0, w_hh0, b_ih0, b_hh0, w_ih1, w_hh1, b_ih1, b_hh1,
      fc_w, fc_b, out, ws_ctl, h0f, h1f);
}

// Round 6
// 4153.477 us; speedup vs baseline: 1.5244x; 1.1107x over previous
//
#include <hip/hip_runtime.h>

#define BB   128   // batch
#define TT   1024  // time steps
#define INP  256   // input dim
#define HH   512   // hidden dim
#define OUTD 256   // output dim
#define GB   16    // batches per group (group = XCD)
#define NG   8     // groups = XCDs
#define NBLK 256   // 1 per CU (88KB LDS cap) -> bijection -> 32 blocks/XCD

typedef float  f32x4  __attribute__((ext_vector_type(4)));
typedef short  short8 __attribute__((ext_vector_type(8)));
typedef unsigned long long u64;

__device__ __forceinline__ unsigned short bf16_rne(float f) {
  union { float f; unsigned u; } v; v.f = f;
  unsigned r = v.u + 0x7fffu + ((v.u >> 16) & 1u);
  return (unsigned short)(r >> 16);
}

// tanh(x) = 1 - 2/(e^{2x}+1) via v_exp_f32 + v_rcp_f32. Abs err ~1e-7,
// far below the bf16 h-state quantization already in the pipeline.
__device__ __forceinline__ float fast_tanh(float x) {
  float t = __builtin_amdgcn_exp2f(x * 2.8853900817779268f); // 2*log2(e)
  return 1.0f - 2.0f * __builtin_amdgcn_rcpf(t + 1.0f);
}

__device__ __forceinline__ short8 pack8(f32x4 a, f32x4 b) {
  union { unsigned short s[8]; short8 v; } u;
  u.s[0] = bf16_rne(a[0]); u.s[1] = bf16_rne(a[1]);
  u.s[2] = bf16_rne(a[2]); u.s[3] = bf16_rne(a[3]);
  u.s[4] = bf16_rne(b[0]); u.s[5] = bf16_rne(b[1]);
  u.s[6] = bf16_rne(b[2]); u.s[7] = bf16_rne(b[3]);
  return u.v;
}

__device__ __forceinline__ short8 load_cvt8(const float* p) {
  const f32x4* q = (const f32x4*)p;
  return pack8(q[0], q[1]);
}

__device__ __forceinline__ f32x4 ntload4(const float* p) {
  return __builtin_nontemporal_load((const f32x4*)p);
}

// XCD-local L2 h-state load: agent-scope RELAXED atomic -> sc0 (L1 bypass),
// compiler batches many outstanding loads under one waitcnt.
__device__ __forceinline__ short8 l2load8(const unsigned short* p) {
  union { u64 q[2]; short8 v; } u;
  const u64* pp = (const u64*)p;
  u.q[0] = __hip_atomic_load(pp,     __ATOMIC_RELAXED, __HIP_MEMORY_SCOPE_AGENT);
  u.q[1] = __hip_atomic_load(pp + 1, __ATOMIC_RELAXED, __HIP_MEMORY_SCOPE_AGENT);
  return u.v;
}

// h-state fragment slots: per (slot, group): [kb(16)][lane(64)][e(8)] bf16 = 16KB.
// Value (b_local, j): kb = j>>5, lane' = ((j>>3)&3)*16 + b_local, e = j&7.
// 4-slot rings. Writer/reader distance bounds under flag scheme: L0-peer lead
// <=1 tick, L0-over-L1 lead <=3 ticks -> no slot collision (checked mod 4).
__device__ __forceinline__ unsigned short* hslot(unsigned short* base, int slot, int g) {
  return base + ((size_t)(slot * NG + g)) * (16 * 64 * 8);
}

__global__ void __launch_bounds__(256, 1) rnn_mfma(
    const float* __restrict__ x,       // [B][T][IN]
    const float* __restrict__ h0init,  // [2][B][H]
    const float* __restrict__ w_ih0,   // [H][IN]
    const float* __restrict__ w_hh0,   // [H][H]
    const float* __restrict__ b_ih0,   // [H]
    const float* __restrict__ b_hh0,   // [H]
    const float* __restrict__ w_ih1,   // [H][H]
    const float* __restrict__ w_hh1,   // [H][H]
    const float* __restrict__ b_ih1,   // [H]
    const float* __restrict__ b_hh1,   // [H]
    const float* __restrict__ fc_w,    // [OUT][H]
    const float* __restrict__ fc_b,    // [OUT]
    float* __restrict__ out,           // [B][OUT]
    unsigned* __restrict__ ws_ctl,     // tickets: [g*32]; flags: +1024 u32, per group 16 x 128B
    unsigned short* __restrict__ h0f,  // h0 ring: 4 slots x NG x 16KB
    unsigned short* __restrict__ h1f)  // h1 ring: 4 slots x NG x 16KB
{
  extern __shared__ char lds_pad[];    // 88KB dynamic -> occupancy cap (1 block/CU)
  (void)lds_pad;
  const int tid = threadIdx.x;

  // ---- claim a role on THIS XCD.
  __shared__ unsigned sh_tk, sh_g;
  if (tid == 0) {
    unsigned xcc;
    asm volatile("s_getreg_b32 %0, hwreg(HW_REG_XCC_ID)" : "=s"(xcc));
    xcc &= 7;
    sh_g  = xcc;
    sh_tk = __hip_atomic_fetch_add(ws_ctl + xcc * 32, 1u,
                                   __ATOMIC_RELAXED, __HIP_MEMORY_SCOPE_AGENT);
  }
  __syncthreads();
  const unsigned ticket = sh_tk;
  const int g = (int)sh_g;
  if (ticket >= 16) return;            // spares exit (R4 showed spinning spares hurt)

  const int role = (int)ticket;        // 0..7: L0 j-slices; 8..15: L1 j-slices
  const bool isL0 = role < 8;
  const int wv   = tid >> 6;
  const int lane = tid & 63;
  const int ln   = lane & 15;
  const int q    = lane >> 4;
  const int j0   = (role & 7) * 64 + wv * 16 + ln;  // weight-frag row (m = lane&15)
  const int jq   = (role & 7) * 64 + wv * 16 + q * 4; // this thread's 4 output j's
  const int bg   = g * GB;

  // Per-block flag lines: flag[b] = 1 after init; = t+2 after completing tick t.
  volatile int* flags  = (volatile int*)(ws_ctl + 1024 + g * 512);
  volatile int* myflag = flags + role * 32;

  // ---- init: h0init -> h0 slot 3, h1init -> h1 slot 3 (plain stores, local L2).
  for (int c = tid; c < 2048; c += 256) {
    int a  = c >> 10;
    int bl = (c >> 6) & 15;
    int j8 = (c & 63) * 8;
    short8 v = load_cvt8(h0init + ((size_t)a * BB + (bg + bl)) * HH + j8);
    unsigned short* dst = hslot(a ? h1f : h0f, 3, g)
        + ((size_t)((j8 >> 5) * 64 + ((j8 >> 3) & 3) * 16 + bl)) * 8;
    *(short8*)dst = v;
  }
  __syncthreads();                     // drain init stores to L2
  if (tid == 0) *myflag = 1;           // init published

  // ---- weight fragments -> registers (MFMA A-operand; row j0, k = kb*32+q*8+e).
  short8 Bf0[24];  // L0: w_ih0 (kb 0..7) then w_hh0 (kb 8..23)
  short8 Bf1[32];  // L1: w_ih1 (kb 0..15) then w_hh1 (kb 16..31)
  if (isL0) {
#pragma unroll
    for (int kb = 0; kb < 24; ++kb) {
      int k = kb * 32 + q * 8;
      const float* src = (k < INP) ? (w_ih0 + (size_t)j0 * INP + k)
                                   : (w_hh0 + (size_t)j0 * HH + (k - INP));
      Bf0[kb] = load_cvt8(src);
    }
  } else {
#pragma unroll
    for (int kb = 0; kb < 32; ++kb) {
      int k = kb * 32 + q * 8;
      const float* src = (k < HH) ? (w_ih1 + (size_t)j0 * HH + k)
                                  : (w_hh1 + (size_t)j0 * HH + (k - HH));
      Bf1[kb] = load_cvt8(src);
    }
  }
  // Per-thread bias vector for its 4 output j's (jq+0..3). 16B-aligned loads.
  f32x4 bias4;
  {
    const float* bi = isL0 ? b_ih0 : b_ih1;
    const float* bh = isL0 ? b_hh0 : b_hh1;
    bias4 = *(const f32x4*)(bi + jq) + *(const f32x4*)(bh + jq);
  }

  short8 xa[8];
  if (isL0) {
    const float* xp = x + ((size_t)(bg + ln) * TT + 0) * INP;
#pragma unroll
    for (int kb = 0; kb < 8; ++kb)
      xa[kb] = pack8(ntload4(xp + kb * 32 + q * 8), ntload4(xp + kb * 32 + q * 8 + 4));
  }

  const f32x4 z = {0.f, 0.f, 0.f, 0.f};
  const int tmax = isL0 ? (TT - 1) : TT;

  // ---- tick loop. L0 tick t: h0(t) = f(x(t), h0(t-1)). Gate: L0 flags >= t+1,
  // L1 flags >= t-1 (slot-reuse guard). L1 tick t (>=1): h1(t-1) =
  // f(h0(t-1), h1(t-2)). Gate A: L1 flags >= t+1 (stale, fast) -> issue Af1;
  // Gate B: L0 flags >= t+1 (the real rendezvous) -> issue Af0.
#pragma unroll 1
  for (int t = 0; t <= tmax; ++t) {
    if (isL0) {
      // x(t+1) NT loads issued BEFORE the gate: HBM latency hides under the
      // poll; the gate barrier's vmcnt(0) drains them for free.
      f32x4 xr[16];
      const bool havex = (t + 1 < TT);
      if (havex) {
        const float* xp = x + ((size_t)(bg + ln) * TT + (t + 1)) * INP;
#pragma unroll
        for (int kb = 0; kb < 8; ++kb) {
          xr[2 * kb]     = ntload4(xp + kb * 32 + q * 8);
          xr[2 * kb + 1] = ntload4(xp + kb * 32 + q * 8 + 4);
        }
      }

      if (tid < 16) {
        volatile int* fp = flags + tid * 32;
        const int thr = (tid < 8) ? (t + 1) : (t - 1);
        while (*fp < thr) {}
      }
      __syncthreads();

      const unsigned short* hp0 = hslot(h0f, (t + 3) & 3, g);  // h0(t-1)
      short8 Af[16];
#pragma unroll
      for (int kb = 0; kb < 16; ++kb)
        Af[kb] = l2load8(hp0 + ((size_t)kb * 64 + lane) * 8);

      f32x4 ac[4] = {z, z, z, z};
#pragma unroll
      for (int kb = 0; kb < 8; ++kb)   // x part first: runs while Af in flight
        ac[kb & 3] = __builtin_amdgcn_mfma_f32_16x16x32_bf16(
            Bf0[kb], xa[kb], ac[kb & 3], 0, 0, 0);
#pragma unroll
      for (int kb = 8; kb < 24; ++kb)
        ac[kb & 3] = __builtin_amdgcn_mfma_f32_16x16x32_bf16(
            Bf0[kb], Af[kb - 8], ac[kb & 3], 0, 0, 0);

      f32x4 d = ac[0] + ac[1] + ac[2] + ac[3];
      // D[m = q*4+r][n = ln]: 4 consecutive j (jq..jq+3), batch = ln.
      // One aligned 8B store; wave's 64x8B fully covers two 256B segments.
      unsigned short* wdst = hslot(h0f, t & 3, g);
      union { unsigned short s[4]; u64 q8; } uu;
#pragma unroll
      for (int r = 0; r < 4; ++r)
        uu.s[r] = bf16_rne(fast_tanh(d[r] + bias4[r]));
      *(u64*)(wdst + (size_t)((jq >> 5) * 64 + ((jq >> 3) & 3) * 16 + ln) * 8
              + (jq & 7)) = uu.q8;
      if (havex) {
#pragma unroll
        for (int kb = 0; kb < 8; ++kb)
          xa[kb] = pack8(xr[2 * kb], xr[2 * kb + 1]);
      }
    } else {
      // ---- gate A: h1(t-2) ready (peers' tick t-1 done). One tick stale in
      // steady state -> ~never spins.
      if (tid >= 8 && tid < 16) {
        volatile int* fp = flags + tid * 32;
        while (*fp < t + 1) {}
      }
      __syncthreads();

      // Af1 (h1(t-2)) issued early: latency hides under gate B's poll.
      const unsigned short* hp1 = hslot(h1f, (t + 2) & 3, g);
      short8 Af1[16];
#pragma unroll
      for (int kb = 0; kb < 16; ++kb)
        Af1[kb] = l2load8(hp1 + ((size_t)kb * 64 + lane) * 8);

      // ---- gate B: h0(t-1) ready — the real rendezvous.
      if (tid < 8) {
        volatile int* fp = flags + tid * 32;
        while (*fp < t + 1) {}
      }
      __syncthreads();

      if (t >= 1) {
        const unsigned short* hp0 = hslot(h0f, (t + 3) & 3, g);  // h0(t-1)
        short8 Af0[16];
#pragma unroll
        for (int kb = 0; kb < 16; ++kb)
          Af0[kb] = l2load8(hp0 + ((size_t)kb * 64 + lane) * 8);

        f32x4 ac[4] = {z, z, z, z};
#pragma unroll
        for (int kb = 0; kb < 16; ++kb)  // h1 part first: Af1 ready, Af0 in flight
          ac[kb & 3] = __builtin_amdgcn_mfma_f32_16x16x32_bf16(
              Bf1[kb + 16], Af1[kb], ac[kb & 3], 0, 0, 0);
#pragma unroll
        for (int kb = 0; kb < 16; ++kb)
          ac[kb & 3] = __builtin_amdgcn_mfma_f32_16x16x32_bf16(
              Bf1[kb], Af0[kb], ac[kb & 3], 0, 0, 0);

        f32x4 d = ac[0] + ac[1] + ac[2] + ac[3];
        unsigned short* wdst = hslot(h1f, (t + 3) & 3, g);  // h1(t-1)
        union { unsigned short s[4]; u64 q8; } uu;
#pragma unroll
        for (int r = 0; r < 4; ++r)
          uu.s[r] = bf16_rne(fast_tanh(d[r] + bias4[r]));
        *(u64*)(wdst + (size_t)((jq >> 5) * 64 + ((jq >> 3) & 3) * 16 + ln) * 8
                + (jq & 7)) = uu.q8;
      }
    }

    __syncthreads();                   // drain this tick's h stores to L2
    if (tid == 0) *myflag = t + 2;     // publish tick completion
  }

  // ---- FC epilogue: out = h1(TT-1) @ fc_w^T + fc_b (slot 3). Wait for all
  // L1 blocks to finish tick TT (flag = TT+2); L0 flags end at TT+1.
  if (tid < 16) {
    volatile int* fp = flags + tid * 32;
    const int thr = (tid < 8) ? (TT + 1) : (TT + 2);
    while (*fp < thr) {}
  }
  __syncthreads();

  if (wv == 0) {
    const unsigned short* hp = hslot(h1f, 3, g);
    const int o_ln = role * 16 + ln;      // fc_w frag row (A-operand, m = ln)
    const int o_q  = role * 16 + q * 4;   // this thread's 4 output cols
    f32x4 ac[4] = {z, z, z, z};
#pragma unroll
    for (int kb = 0; kb < 16; ++kb) {
      int k = kb * 32 + q * 8;
      short8 Bfc = load_cvt8(fc_w + (size_t)o_ln * HH + k);
      short8 Af  = l2load8(hp + ((size_t)kb * 64 + lane) * 8);
      ac[kb & 3] = __builtin_amdgcn_mfma_f32_16x16x32_bf16(
          Bfc, Af, ac[kb & 3], 0, 0, 0);
    }
    // D[m = q*4+r][n = ln]: out[bg+ln][o_q + r] -> one 16B coalesced store.
    f32x4 fb = *(const f32x4*)(fc_b + o_q);
    f32x4 v = ac[0] + ac[1] + ac[2] + ac[3] + fb;
    *(f32x4*)(out + (size_t)(bg + ln) * OUTD + o_q) = v;
  }
}

extern "C" void kernel_launch(void* const* d_in, const int* in_sizes, int n_in,
                              void* d_out, int out_size, void* d_ws, size_t ws_size,
                              hipStream_t stream) {
  (void)in_sizes; (void)n_in; (void)out_size; (void)ws_size;

  const float* x      = (const float*)d_in[0];
  const float* h0init = (const float*)d_in[1];
  const float* w_ih0  = (const float*)d_in[2];
  const float* w_hh0  = (const float*)d_in[3];
  const float* b_ih0  = (const float*)d_in[4];
  const float* b_hh0  = (const float*)d_in[5];
  const float* w_ih1  = (const float*)d_in[6];
  const float* w_hh1  = (const float*)d_in[7];
  const float* b_ih1  = (const float*)d_in[8];
  const float* b_hh1  = (const float*)d_in[9];
  const float* fc_w   = (const float*)d_in[10];
  const float* fc_b   = (const float*)d_in[11];
  float* out = (float*)d_out;

  // ws: [0,32768) tickets + flags (zeroed); then h0 ring 512KB; h1 ring 512KB
  unsigned* ws_ctl = (unsigned*)d_ws;
  unsigned short* h0f = (unsigned short*)((char*)d_ws + 32768);
  unsigned short* h1f = h0f + 4 * NG * (16 * 64 * 8);

  hipMemsetAsync(d_ws, 0, 32768, stream);

  rnn_mfma<<<dim3(NBLK), dim3(256), 90112, stream>>>(
      x, h0init, w_ih0, w_hh0, b_ih0, b_hh0, w_ih1, w_hh1, b_ih1, b_hh1,
      fc_w, fc_b, out, ws_ctl, h0f, h1f);
}